// Round 3
// baseline (821.526 us; speedup 1.0000x reference)
//
#include <hip/hip_runtime.h>

// MaxUnpooling2D scatter-add, privatized per (b,c) output plane — half-plane
// variant for occupancy.
// updates/mask: [32,64,64,128], out: [32,128,128,128] f32.
// bin = mask >> 7 in [0,16384): out[b, bin>>7... ] i.e. out flat = (b<<21)|(bin<<7)|c.
// Each block owns one (b,c) plane, processed as two 32 KiB y-halves:
//   - (u, bin) register-cached once (no double fetch)
//   - LDS atomics within the half, plain stores out (no global atomics/memset)
// 32 KiB LDS -> 5 blocks/CU (vs 2 at 64 KiB): latency hiding for the
// inherently uncoalesced per-lane 4B loads/stores.
//
// blockIdx swizzle: the 16 blocks covering channels [16k,16k+16) of a batch
// share every 64B line; give them equal blockIdx%8 (same XCD) + adjacent
// rank so reads hit L2 once and 4B-dirty stores merge into full lines.

#define HWC (64 * 64 * 128)   // 2^19 input elements per batch
#define HALF 8192             // half-plane bins (y in one 64-row half)

__global__ __launch_bounds__(256, 4) void unpool_plane2(
    const float* __restrict__ upd, const int* __restrict__ mask,
    float* __restrict__ out)
{
    __shared__ float plane[HALF];   // 32 KiB

    int bid    = blockIdx.x;
    int span   = bid >> 7;
    int within = bid & 127;
    int r      = within & 7;
    int cLo    = within >> 3;
    int g      = span * 8 + r;
    int b      = g >> 3;
    int c      = (g & 7) * 16 + cLo;

    int t = threadIdx.x;

    const float* ub = upd  + (size_t)b * HWC + c;
    const int*   mb = mask + (size_t)b * HWC + c;

    // register-cache this plane's 4096 inputs (16 per thread)
    float u[16];
    int   bin[16];
    #pragma unroll
    for (int k = 0; k < 16; ++k) {
        int pos = t + k * 256;
        u[k]   = ub[(size_t)pos * 128];
        bin[k] = mb[(size_t)pos * 128] >> 7;    // (y,x) bin, 0..16383
    }

    float* ob = out + ((size_t)b << 21) + c;

    #pragma unroll
    for (int half = 0; half < 2; ++half) {
        // zero the half-plane (float4 x 8 per thread = 32 KiB)
        float4* p4 = (float4*)plane;
        #pragma unroll
        for (int k = 0; k < 8; ++k)
            p4[t + k * 256] = make_float4(0.f, 0.f, 0.f, 0.f);
        __syncthreads();

        // accumulate the bins belonging to this half (predicated ds_add)
        #pragma unroll
        for (int k = 0; k < 16; ++k) {
            if ((bin[k] >> 13) == half)
                atomicAdd(&plane[bin[k] & (HALF - 1)], u[k]);
        }
        __syncthreads();

        // write the half-plane: out[b, y, x, c], stride 128 floats
        #pragma unroll
        for (int k = 0; k < 32; ++k) {
            int p = t + k * 256;
            ob[(size_t)(p + half * HALF) * 128] = plane[p];
        }
        if (half == 0) __syncthreads();   // stores read plane; next iter rewrites it
    }
}

extern "C" void kernel_launch(void* const* d_in, const int* in_sizes, int n_in,
                              void* d_out, int out_size, void* d_ws, size_t ws_size,
                              hipStream_t stream) {
    const float* upd  = (const float*)d_in[0];
    const int*   mask = (const int*)d_in[1];
    float*       out  = (float*)d_out;

    // 32 batches * 128 channels = 4096 plane-workgroups; every output element
    // is written exactly once -> no memset.
    unpool_plane2<<<4096, 256, 0, stream>>>(upd, mask, out);
}

// Round 4
// 455.716 us; speedup vs baseline: 1.8027x; 1.8027x over previous
//
#include <hip/hip_runtime.h>

// MaxUnpooling2D scatter-add — 4-channel / quarter-plane privatization.
// updates/mask: [32,64,64,128] f32/i32, out: [32,128,128,128] f32.
// out flat = (b<<21) | (bin<<7) | c  where bin = mask>>7 in [0,16384).
//
// R3 lesson: bottleneck is VMEM line-request rate (4B accesses at 512B
// stride -> 1 line-request each; ~100M total). Fix: each block owns 4
// consecutive channels so reads are int4/float4 (4x fewer requests) and
// output stores are float4 (4x fewer). LDS holds 4 channels x one y-quarter
// (4096 bins) channel-interleaved = 64 KiB; 4 passes over quarters replay a
// register-cached (u4,m4) set (128 VGPRs, fits under the 256-VGPR cap at
// 2 blocks/CU) so input is fetched exactly once.
//
// XCD swizzle: b = bid&31 -> all 32 channel-group blocks of a batch share
// bid%8 (same XCD); they jointly cover each 512B input/output line, so L2
// serves one HBM fetch per line and merges 16B-dirty stores into full lines.

#define HWC (64 * 64 * 128)   // 2^19 input elements per batch
#define QBINS 4096            // bins per y-quarter (32 rows x 128 x)

__global__ __launch_bounds__(256, 2) void unpool_q4(
    const float* __restrict__ upd, const int* __restrict__ mask,
    float* __restrict__ out)
{
    __shared__ float acc[QBINS * 4];   // 64 KiB, layout [bin][4 channels]

    int bid = blockIdx.x;
    int b   = bid & 31;
    int c0  = (bid >> 5) << 2;         // channel group base, 0..124

    int t = threadIdx.x;

    const float4* ub = (const float4*)(upd  + (size_t)b * HWC + c0);
    const int4*   mb = (const int4*)  (mask + (size_t)b * HWC + c0);
    float*        ob = out + ((size_t)b << 21) + c0;

    // Register-cache this block's full input: 16 pos/thread x (float4+int4).
    float4 u[16];
    int4   m[16];
    #pragma unroll
    for (int k = 0; k < 16; ++k) {
        int pos = t + k * 256;         // (h,w) position 0..4095
        u[k] = ub[pos * 32];           // float4 stride = 128 floats
        m[k] = mb[pos * 32];
    }

    float4* a4 = (float4*)acc;

    for (int q = 0; q < 4; ++q) {
        // zero 64 KiB (16 float4 per thread)
        #pragma unroll
        for (int k = 0; k < 16; ++k)
            a4[t + k * 256] = make_float4(0.f, 0.f, 0.f, 0.f);
        __syncthreads();

        // scatter this quarter's elements into LDS (ds_add, no return)
        #pragma unroll
        for (int k = 0; k < 16; ++k) {
            int b0 = m[k].x >> 7; if ((b0 >> 12) == q) atomicAdd(&acc[((b0 & 4095) << 2) + 0], u[k].x);
            int b1 = m[k].y >> 7; if ((b1 >> 12) == q) atomicAdd(&acc[((b1 & 4095) << 2) + 1], u[k].y);
            int b2 = m[k].z >> 7; if ((b2 >> 12) == q) atomicAdd(&acc[((b2 & 4095) << 2) + 2], u[k].z);
            int b3 = m[k].w >> 7; if ((b3 >> 12) == q) atomicAdd(&acc[((b3 & 4095) << 2) + 3], u[k].w);
        }
        __syncthreads();

        // store the quarter: out[b, bin, c0..c0+3] as float4, bin = q*4096+p
        #pragma unroll
        for (int k = 0; k < 16; ++k) {
            int p = t + k * 256;
            float4 v = a4[p];
            *(float4*)(ob + (size_t)(q * QBINS + p) * 128) = v;
        }
        if (q < 3) __syncthreads();    // next pass rewrites acc
    }
}

extern "C" void kernel_launch(void* const* d_in, const int* in_sizes, int n_in,
                              void* d_out, int out_size, void* d_ws, size_t ws_size,
                              hipStream_t stream) {
    const float* upd  = (const float*)d_in[0];
    const int*   mask = (const int*)d_in[1];
    float*       out  = (float*)d_out;

    // 32 batches x 32 channel-groups; every output element written exactly
    // once -> no memset, no global atomics.
    unpool_q4<<<1024, 256, 0, stream>>>(upd, mask, out);
}